// Round 1
// 132.866 us; speedup vs baseline: 1.0243x; 1.0243x over previous
//
#include <hip/hip_runtime.h>
#include <math.h>

#define KEYS 11
#define NSTACK 4
#define NB 16
#define HH 128
#define WW 128
#define HW (HH * WW)

// native vector type so __builtin_nontemporal_load lowers to a 16B nt load
typedef float f4 __attribute__((ext_vector_type(4)));

__global__ void kp_zero_out(float* out) {
    out[threadIdx.x] = 0.0f;  // 128 output floats
}

__global__ __launch_bounds__(256) void kp_loss_kernel(
    const float* __restrict__ cp,    // (16, 4, 22, 128, 128)
    const float* __restrict__ heat,  // (16, 11, 128, 128)
    const float* __restrict__ lab,   // (16, 11, 11)
    float* __restrict__ out)         // 128: heat_loss(64) then label_loss(64)
{
    // XCD-aware decode: grid = 704 blocks, 8 XCDs round-robin on blockIdx%8.
    // Per XCD: 88 blocks = 22 (b,k) groups x 4 stacks. Each XCD owns exactly
    // 2 b-values (22 = 2*KEYS) -> heat working set/XCD = 22*64KB = 1.4MB < 4MB L2.
    // All 4 stacks of a (b,k) share one XCD => heat fetched from HBM once, L2-hit 3x.
    const int g   = blockIdx.x;
    const int xcd = g & 7;               // assumed XCD id (perf-only assumption)
    const int j   = g >> 3;              // 0..87 within XCD
    const int s   = j & 3;
    const int grp = xcd * 22 + (j >> 2); // 0..175  == b*KEYS + k
    const int b   = grp / KEYS;
    const int k   = grp % KEYS;
    const int bs  = b * NSTACK + s;

    const float* __restrict__ hm = cp + ((size_t)((bs) * (2 * KEYS) + k)) * HW;
    const float* __restrict__ ht = heat + ((size_t)(b * KEYS + k)) * HW;

    const int tid = threadIdx.x;
    float sum  = 0.0f;
    float vmax = -INFINITY;
    int   imax = 0;

    const f4* __restrict__ hm4 = (const f4*)hm;
    const f4* __restrict__ ht4 = (const f4*)ht;

    #pragma unroll 4
    for (int i = tid; i < HW / 4; i += 256) {
        f4 a = __builtin_nontemporal_load(hm4 + i);  // hm is read exactly once: stream it
        f4 c = ht4[i];                               // heat is reused 4x: keep cached
        float d0 = a[0] - c[0], d1 = a[1] - c[1], d2 = a[2] - c[2], d3 = a[3] - c[3];
        sum += d0 * d0 + d1 * d1 + d2 * d2 + d3 * d3;
        int base = i * 4;
        // strictly-greater keeps first occurrence (indices increase per thread)
        if (a[0] > vmax) { vmax = a[0]; imax = base;     }
        if (a[1] > vmax) { vmax = a[1]; imax = base + 1; }
        if (a[2] > vmax) { vmax = a[2]; imax = base + 2; }
        if (a[3] > vmax) { vmax = a[3]; imax = base + 3; }
    }

    // wave-64 reduction (sum + argmax with first-index tie break)
    #pragma unroll
    for (int off = 32; off > 0; off >>= 1) {
        float ov = __shfl_down(vmax, off);
        int   oi = __shfl_down(imax, off);
        float os = __shfl_down(sum,  off);
        sum += os;
        if (ov > vmax || (ov == vmax && oi < imax)) { vmax = ov; imax = oi; }
    }

    __shared__ float s_sum[4];
    __shared__ float s_v[4];
    __shared__ int   s_i[4];
    const int wave = tid >> 6;
    if ((tid & 63) == 0) { s_sum[wave] = sum; s_v[wave] = vmax; s_i[wave] = imax; }
    __syncthreads();

    if (tid == 0) {
        #pragma unroll
        for (int w = 1; w < 4; w++) {
            sum += s_sum[w];
            if (s_v[w] > vmax || (s_v[w] == vmax && s_i[w] < imax)) {
                vmax = s_v[w]; imax = s_i[w];
            }
        }
        atomicAdd(&out[bs], sum);

        // ---- label loss for this (b, s, k) ----
        const float* __restrict__ lb = cp + ((size_t)((bs) * (2 * KEYS) + KEYS + k)) * HW;
        const float* __restrict__ L  = lab + (size_t)(b * KEYS + k) * 11;
        float gx = L[9], gy = L[10];
        bool valid = (gx > 0.0f) && (gy > 0.0f) && (gx < (float)HH) && (gy < (float)WW);
        if (valid) {
            float xf = (float)(imax / WW);   // row (x = index // m, m == W == 128)
            float yf = (float)(imax % WW);   // col
            float dx = gx + L[7] - xf - lb[7];
            float dy = gy + L[8] - yf - lb[8];
            float loss = dx * dx + dy * dy;
            float cm = 1.0f - vmax;
            loss += cm * cm;
            #pragma unroll
            for (int j2 = 0; j2 < 7; j2++) {
                float d = lb[j2] - L[j2];
                loss += d * d;
            }
            atomicAdd(&out[64 + bs], loss);
        }
    }
}

extern "C" void kernel_launch(void* const* d_in, const int* in_sizes, int n_in,
                              void* d_out, int out_size, void* d_ws, size_t ws_size,
                              hipStream_t stream) {
    const float* cp   = (const float*)d_in[0];
    const float* heat = (const float*)d_in[1];
    const float* lab  = (const float*)d_in[2];
    float* out = (float*)d_out;

    kp_zero_out<<<1, 128, 0, stream>>>(out);
    kp_loss_kernel<<<NB * NSTACK * KEYS, 256, 0, stream>>>(cp, heat, lab, out);
}